// Round 9
// baseline (304.714 us; speedup 1.0000x reference)
//
#include <hip/hip_runtime.h>
#include <hip/hip_bf16.h>
#include <hip/hip_cooperative_groups.h>

namespace cg = cooperative_groups;

// LINK forward: out[i, o] = b[o] + sum over edges (i -> j) of W[o, j]
// N=100000, OUT=64, E=3200000.
//
// R9: R8 left ~45us of launch gaps between 3 kernels. Fuse everything into
// ONE cooperative kernel: 256 blocks x 1024 threads, ~87KB LDS -> exactly
// 1 block/CU (co-residency guaranteed), grid.sync() between phases:
//   phase 0: transpose W -> bf16x2 WTh[N][32] (tiles strided); init cursors
//   phase 1: R8 partition (LDS counting sort of 12.5K-edge chunk -> slab
//            writes contiguous per (block,bucket) run)
//   phase 2: gather with dynamic bucket queue (atomic ticket): per-bucket
//            LDS counting sort + half-wave-per-edge bf16 gather, f32 accum.

#define PB    256          // grid blocks (1 per CU)
#define PT    1024         // threads per block (16 waves)
#define EPB   12544        // edge capacity per partition chunk
#define SLAB  2560         // per-bucket slab capacity (mean 2048 + 11 sigma)
#define NFX   2048         // max fine buckets (N <= 131072)
#define OUTC  64

__device__ inline unsigned f2bf(float x) {           // RNE f32 -> bf16 bits
    unsigned u = __float_as_uint(x);
    return (u + 0x7FFFu + ((u >> 16) & 1u)) >> 16;
}
__device__ inline float bf_lo(unsigned u) { return __uint_as_float(u << 16); }
__device__ inline float bf_hi(unsigned u) { return __uint_as_float(u & 0xFFFF0000u); }

__global__ __launch_bounds__(PT) void mega(const int* __restrict__ rows,
                                           const int* __restrict__ cols,
                                           const float* __restrict__ W,
                                           const float* __restrict__ bias,
                                           unsigned* __restrict__ WTh,
                                           int* __restrict__ gcur,
                                           unsigned* __restrict__ packed,
                                           int* __restrict__ gq,
                                           float* __restrict__ out,
                                           int E, int N, int NF) {
    cg::grid_group grid = cg::this_grid();
    __shared__ union {
        float tile[64][65];                                   // phase 0 (16.6 KB)
        struct {                                              // phase 1 (87 KB)
            unsigned lbuf[EPB];
            int cnt[NFX];
            int loff[NFX + 1];
            int lcur[NFX];
            int gbase[NFX];
            int partial[PT];
        } p1;
        struct {                                              // phase 2 (11 KB)
            unsigned scol[SLAB];
            int cnt[64], off0[64], tend[64], cur[64];
            int bkt;
        } p2;
    } sh;

    const int tid = threadIdx.x;

    // ---------------- phase 0: transpose + cursor init ----------------
    for (int t = blockIdx.x; t * 64 < N; t += gridDim.x) {
        const int n0 = t * 64;
        {   // load one 64x64 f32 tile: 1024 float4s, one per thread
            int o = tid >> 4, q = tid & 15;
            int nn = n0 + q * 4;
            if (nn + 3 < N) {
                float4 v = *(const float4*)(W + (size_t)o * N + nn);
                sh.tile[o][q * 4 + 0] = v.x;
                sh.tile[o][q * 4 + 1] = v.y;
                sh.tile[o][q * 4 + 2] = v.z;
                sh.tile[o][q * 4 + 3] = v.w;
            } else {
                for (int j = 0; j < 4; ++j)
                    sh.tile[o][q * 4 + j] = (nn + j < N) ? W[(size_t)o * N + nn + j] : 0.f;
            }
        }
        __syncthreads();
        #pragma unroll
        for (int k2 = 0; k2 < 2; ++k2) {
            int idx = tid + k2 * PT;
            int nl = idx >> 5, u = idx & 31;
            int nn = n0 + nl;
            if (nn < N)
                WTh[(size_t)nn * 32 + u] =
                    f2bf(sh.tile[2 * u][nl]) | (f2bf(sh.tile[2 * u + 1][nl]) << 16);
        }
        __syncthreads();
    }
    if (blockIdx.x == 0) {
        for (int i = tid; i < NF; i += PT) gcur[i] = i * SLAB;
        if (tid == 0)
            __hip_atomic_store(gq, 0, __ATOMIC_RELEASE, __HIP_MEMORY_SCOPE_AGENT);
    }
    grid.sync();

    // ---------------- phase 1: partition (LDS counting sort -> slabs) ----------------
    const int nchunks = (E + EPB - 1) / EPB;
    for (int c = blockIdx.x; c < nchunks; c += gridDim.x) {
        const int base = c * EPB;
        const int lim  = min(E, base + EPB);
        const int nE   = lim - base;

        for (int i = tid; i < NFX; i += PT) sh.p1.cnt[i] = 0;
        __syncthreads();

        // pass A: count
        for (int e = base + tid * 4; e + 3 < lim; e += PT * 4) {
            int4 r = *(const int4*)(rows + e);
            atomicAdd(&sh.p1.cnt[r.x >> 6], 1);
            atomicAdd(&sh.p1.cnt[r.y >> 6], 1);
            atomicAdd(&sh.p1.cnt[r.z >> 6], 1);
            atomicAdd(&sh.p1.cnt[r.w >> 6], 1);
        }
        {
            int ts = base + (nE & ~3);
            for (int e = ts + tid; e < lim; e += PT)
                atomicAdd(&sh.p1.cnt[rows[e] >> 6], 1);
        }
        __syncthreads();

        // block exclusive scan of 2048 counters (2 per thread)
        int v0 = sh.p1.cnt[2 * tid], v1 = sh.p1.cnt[2 * tid + 1];
        int s  = v0 + v1;
        sh.p1.partial[tid] = s;
        __syncthreads();
        for (int off = 1; off < PT; off <<= 1) {
            int t = 0;
            if (tid >= off) t = sh.p1.partial[tid - off];
            __syncthreads();
            if (tid >= off) sh.p1.partial[tid] += t;
            __syncthreads();
        }
        int ex = sh.p1.partial[tid] - s;
        sh.p1.loff[2 * tid]     = ex;
        sh.p1.loff[2 * tid + 1] = ex + v0;
        sh.p1.lcur[2 * tid]     = ex;
        sh.p1.lcur[2 * tid + 1] = ex + v0;
        if (tid == PT - 1) sh.p1.loff[NFX] = sh.p1.partial[PT - 1];
        __syncthreads();

        // reserve global slab ranges (1 atomic per non-empty bucket)
        for (int b = tid; b < NF; b += PT) {
            int cc = sh.p1.cnt[b];
            sh.p1.gbase[b] = cc ? atomicAdd(&gcur[b], cc) : 0;
        }
        __syncthreads();

        // pass B: scatter into LDS in bucket order (edges re-read, L2-hot)
        for (int e = base + tid * 4; e + 3 < lim; e += PT * 4) {
            int4 r  = *(const int4*)(rows + e);
            int4 cc = *(const int4*)(cols + e);
            int p0 = atomicAdd(&sh.p1.lcur[r.x >> 6], 1);
            int p1 = atomicAdd(&sh.p1.lcur[r.y >> 6], 1);
            int p2 = atomicAdd(&sh.p1.lcur[r.z >> 6], 1);
            int p3 = atomicAdd(&sh.p1.lcur[r.w >> 6], 1);
            sh.p1.lbuf[p0] = ((unsigned)(r.x & 63) << 17) | (unsigned)cc.x;
            sh.p1.lbuf[p1] = ((unsigned)(r.y & 63) << 17) | (unsigned)cc.y;
            sh.p1.lbuf[p2] = ((unsigned)(r.z & 63) << 17) | (unsigned)cc.z;
            sh.p1.lbuf[p3] = ((unsigned)(r.w & 63) << 17) | (unsigned)cc.w;
        }
        {
            int ts = base + (nE & ~3);
            for (int e = ts + tid; e < lim; e += PT) {
                int r = rows[e];
                int p = atomicAdd(&sh.p1.lcur[r >> 6], 1);
                sh.p1.lbuf[p] = ((unsigned)(r & 63) << 17) | (unsigned)cols[e];
            }
        }
        __syncthreads();

        // pass C: copy runs to global slabs (contiguous within runs)
        const int chunk = (nE + PT - 1) / PT;
        int i0 = tid * chunk;
        int i1 = min(nE, i0 + chunk);
        if (i0 < i1) {
            int lo = 0, hi = NFX;
            while (hi - lo > 1) {
                int mid = (lo + hi) >> 1;
                if (sh.p1.loff[mid] <= i0) lo = mid; else hi = mid;
            }
            int b = lo;
            for (int i = i0; i < i1; ++i) {
                while (i >= sh.p1.loff[b + 1]) ++b;
                packed[sh.p1.gbase[b] + (i - sh.p1.loff[b])] = sh.p1.lbuf[i];
            }
        }
        __syncthreads();
    }
    grid.sync();

    // ---------------- phase 2: gather with dynamic bucket queue ----------------
    const int lane = tid & 63;
    const int w    = tid >> 6;            // wave 0..15
    const int hl   = lane & 31;
    const int half = lane >> 5;
    const float bx = bias[2 * hl];
    const float by = bias[2 * hl + 1];

    for (;;) {
        if (tid == 0) sh.p2.bkt = atomicAdd(gq, 1);
        __syncthreads();
        const int b = sh.p2.bkt;
        if (b >= NF) break;
        const int start = b * SLAB;
        int size = gcur[b] - start;
        if (size > SLAB) size = SLAB;

        if (tid < 64) sh.p2.cnt[tid] = 0;
        __syncthreads();
        for (int e = tid; e < size; e += PT)
            atomicAdd(&sh.p2.cnt[packed[start + e] >> 17], 1);
        __syncthreads();
        if (tid < 64) {      // wave-0 shfl scan of 64 counters
            int v = sh.p2.cnt[tid];
            int inc = v;
            #pragma unroll
            for (int d = 1; d < 64; d <<= 1) {
                int t = __shfl_up(inc, d, 64);
                if (lane >= d) inc += t;
            }
            sh.p2.tend[tid] = inc;
            sh.p2.off0[tid] = inc - v;
            sh.p2.cur[tid]  = inc - v;
        }
        __syncthreads();
        for (int e = tid; e < size; e += PT) {
            unsigned u = packed[start + e];
            int p = atomicAdd(&sh.p2.cur[u >> 17], 1);
            sh.p2.scol[p] = u & 0x1FFFFu;
        }
        __syncthreads();

        for (int r = w; r < 64; r += 16) {       // 4 nodes per wave
            const int nn = b * 64 + r;
            if (nn >= N) break;
            int s = sh.p2.off0[r], t = sh.p2.tend[r];
            float ax = 0.f, ay = 0.f;
            int e = s + half;
            for (; e + 14 < t; e += 16) {
                unsigned c0 = sh.p2.scol[e + 0],  c1 = sh.p2.scol[e + 2];
                unsigned c2 = sh.p2.scol[e + 4],  c3 = sh.p2.scol[e + 6];
                unsigned c4 = sh.p2.scol[e + 8],  c5 = sh.p2.scol[e + 10];
                unsigned c6 = sh.p2.scol[e + 12], c7 = sh.p2.scol[e + 14];
                unsigned u0 = WTh[(size_t)c0 * 32 + hl];
                unsigned u1 = WTh[(size_t)c1 * 32 + hl];
                unsigned u2 = WTh[(size_t)c2 * 32 + hl];
                unsigned u3 = WTh[(size_t)c3 * 32 + hl];
                unsigned u4 = WTh[(size_t)c4 * 32 + hl];
                unsigned u5 = WTh[(size_t)c5 * 32 + hl];
                unsigned u6 = WTh[(size_t)c6 * 32 + hl];
                unsigned u7 = WTh[(size_t)c7 * 32 + hl];
                ax += bf_lo(u0); ay += bf_hi(u0);
                ax += bf_lo(u1); ay += bf_hi(u1);
                ax += bf_lo(u2); ay += bf_hi(u2);
                ax += bf_lo(u3); ay += bf_hi(u3);
                ax += bf_lo(u4); ay += bf_hi(u4);
                ax += bf_lo(u5); ay += bf_hi(u5);
                ax += bf_lo(u6); ay += bf_hi(u6);
                ax += bf_lo(u7); ay += bf_hi(u7);
            }
            for (; e < t; e += 2) {
                unsigned u = WTh[(size_t)sh.p2.scol[e] * 32 + hl];
                ax += bf_lo(u); ay += bf_hi(u);
            }
            ax += __shfl_xor(ax, 32);
            ay += __shfl_xor(ay, 32);
            if (half == 0) {
                float2 o;
                o.x = ax + bx;
                o.y = ay + by;
                ((float2*)out)[(size_t)nn * 32 + hl] = o;
            }
        }
        __syncthreads();
    }
}

extern "C" void kernel_launch(void* const* d_in, const int* in_sizes, int n_in,
                              void* d_out, int out_size, void* d_ws, size_t ws_size,
                              hipStream_t stream) {
    const int*   edges = (const int*)d_in[0];    // [2, E]: rows then cols
    const float* W     = (const float*)d_in[1];  // [64, N]
    const float* bias  = (const float*)d_in[2];  // [64]
    float*       out   = (float*)d_out;          // [N, 64]

    int E  = in_sizes[0] / 2;
    int N  = in_sizes[1] / OUTC;
    int NF = (N + 63) / 64;                      // 1563 fine buckets

    // workspace layout (~29 MB)
    char* ws = (char*)d_ws;
    size_t off = 0;
    unsigned* WTh = (unsigned*)(ws + off); off += (size_t)N * 32 * sizeof(unsigned);
    off = (off + 255) & ~(size_t)255;
    int* gcur = (int*)(ws + off);          off += (size_t)NF * sizeof(int);
    off = (off + 255) & ~(size_t)255;
    int* gq = (int*)(ws + off);            off += 256;
    unsigned* packed = (unsigned*)(ws + off); off += (size_t)NF * SLAB * sizeof(unsigned);
    (void)ws_size;

    const int* rows = edges;
    const int* cols = edges + E;

    void* args[] = { (void*)&rows, (void*)&cols, (void*)&W, (void*)&bias,
                     (void*)&WTh, (void*)&gcur, (void*)&packed, (void*)&gq,
                     (void*)&out, (void*)&E, (void*)&N, (void*)&NF };
    hipLaunchCooperativeKernel((void*)mega, dim3(PB), dim3(PT), args, 0, stream);
}

// Round 10
// 179.261 us; speedup vs baseline: 1.6998x; 1.6998x over previous
//
#include <hip/hip_runtime.h>
#include <hip/hip_bf16.h>

// LINK forward: out[i, o] = b[o] + sum over edges (i -> j) of W[o, j]
// N=100000, OUT=64, E=3200000.
//
// R10: revert R9 fusion (1-block/CU union LDS + coop-launch overhead cost
// 124us). Back to R8 pipeline with two changes:
//  - part_trans: transpose fused as a prologue of partition (3 launches -> 2;
//    gcur = offset-in-slab, initialized by hipMemsetAsync(0))
//  - sort_gather2: 8-lane group per NODE, uint4 WTh loads (16B/lane sweet
//    spot, 8 edges in flight per wave instr, NO shfl reduction), float4
//    stores; per-wave sort histograms/cursors (4x less LDS atomic contention)

#define OUTC 64
#define NFX  2048          // max fine buckets
#define SLAB 2560          // per-bucket slab capacity (mean 2048 + 11 sigma)
#define EPB  12544         // edges per partition chunk
#define PT   1024

__device__ inline unsigned f2bf(float x) {           // RNE f32 -> bf16 bits
    unsigned u = __float_as_uint(x);
    return (u + 0x7FFFu + ((u >> 16) & 1u)) >> 16;
}
__device__ inline float bf_lo(unsigned u) { return __uint_as_float(u << 16); }
__device__ inline float bf_hi(unsigned u) { return __uint_as_float(u & 0xFFFF0000u); }

// ---------------- A: fused transpose + partition ----------------
__global__ __launch_bounds__(PT) void part_trans(const int* __restrict__ rows,
                                                 const int* __restrict__ cols,
                                                 const float* __restrict__ W,
                                                 unsigned* __restrict__ WTh,
                                                 int* __restrict__ gcur,
                                                 unsigned* __restrict__ packed,
                                                 int E, int N, int NF) {
    __shared__ union {
        float tile[64][65];                  // transpose (16.6 KB)
        struct {                             // partition (~87 KB)
            unsigned lbuf[EPB];
            int cnt[NFX];
            int loff[NFX + 1];
            int lcur[NFX];
            int gbase[NFX];
            int partial[PT];
        } p1;
    } sh;
    const int tid = threadIdx.x;

    // ---- phase 0: transpose W[64][N] -> WTh[N][32] bf16x2 ----
    const int ntiles = (N + 63) >> 6;
    for (int t = blockIdx.x; t < ntiles; t += gridDim.x) {
        const int n0 = t * 64;
        {   // 1024 float4 loads, one per thread
            int o = tid >> 4, q = tid & 15;
            int nn = n0 + q * 4;
            if (nn + 3 < N) {
                float4 v = *(const float4*)(W + (size_t)o * N + nn);
                sh.tile[o][q * 4 + 0] = v.x;
                sh.tile[o][q * 4 + 1] = v.y;
                sh.tile[o][q * 4 + 2] = v.z;
                sh.tile[o][q * 4 + 3] = v.w;
            } else {
                for (int j = 0; j < 4; ++j)
                    sh.tile[o][q * 4 + j] = (nn + j < N) ? W[(size_t)o * N + nn + j] : 0.f;
            }
        }
        __syncthreads();
        #pragma unroll
        for (int k2 = 0; k2 < 2; ++k2) {
            int idx = tid + k2 * PT;
            int nl = idx >> 5, u = idx & 31;
            int nn = n0 + nl;
            if (nn < N)
                WTh[(size_t)nn * 32 + u] =
                    f2bf(sh.tile[2 * u][nl]) | (f2bf(sh.tile[2 * u + 1][nl]) << 16);
        }
        __syncthreads();
    }

    // ---- phase 1: partition (block LDS counting sort -> slab runs) ----
    const int nchunks = (E + EPB - 1) / EPB;     // 256
    for (int c = blockIdx.x; c < nchunks; c += gridDim.x) {
        const int base = c * EPB;
        const int lim  = min(E, base + EPB);
        const int nE   = lim - base;

        for (int i = tid; i < NFX; i += PT) sh.p1.cnt[i] = 0;
        __syncthreads();

        // pass A: count
        for (int e = base + tid * 4; e + 3 < lim; e += PT * 4) {
            int4 r = *(const int4*)(rows + e);
            atomicAdd(&sh.p1.cnt[r.x >> 6], 1);
            atomicAdd(&sh.p1.cnt[r.y >> 6], 1);
            atomicAdd(&sh.p1.cnt[r.z >> 6], 1);
            atomicAdd(&sh.p1.cnt[r.w >> 6], 1);
        }
        {
            int ts = base + (nE & ~3);
            for (int e = ts + tid; e < lim; e += PT)
                atomicAdd(&sh.p1.cnt[rows[e] >> 6], 1);
        }
        __syncthreads();

        // block exclusive scan of 2048 counters (2 per thread)
        int v0 = sh.p1.cnt[2 * tid], v1 = sh.p1.cnt[2 * tid + 1];
        int s  = v0 + v1;
        sh.p1.partial[tid] = s;
        __syncthreads();
        for (int off = 1; off < PT; off <<= 1) {
            int t = 0;
            if (tid >= off) t = sh.p1.partial[tid - off];
            __syncthreads();
            if (tid >= off) sh.p1.partial[tid] += t;
            __syncthreads();
        }
        int ex = sh.p1.partial[tid] - s;
        sh.p1.loff[2 * tid]     = ex;
        sh.p1.loff[2 * tid + 1] = ex + v0;
        sh.p1.lcur[2 * tid]     = ex;
        sh.p1.lcur[2 * tid + 1] = ex + v0;
        if (tid == PT - 1) sh.p1.loff[NFX] = sh.p1.partial[PT - 1];
        __syncthreads();

        // reserve global slab ranges (gcur = offset within slab)
        for (int b = tid; b < NF; b += PT) {
            int cc = sh.p1.cnt[b];
            sh.p1.gbase[b] = b * SLAB + (cc ? atomicAdd(&gcur[b], cc) : 0);
        }
        __syncthreads();

        // pass B: scatter into LDS in bucket order (edges re-read, L2-hot)
        for (int e = base + tid * 4; e + 3 < lim; e += PT * 4) {
            int4 r  = *(const int4*)(rows + e);
            int4 cc = *(const int4*)(cols + e);
            int p0 = atomicAdd(&sh.p1.lcur[r.x >> 6], 1);
            int p1 = atomicAdd(&sh.p1.lcur[r.y >> 6], 1);
            int p2 = atomicAdd(&sh.p1.lcur[r.z >> 6], 1);
            int p3 = atomicAdd(&sh.p1.lcur[r.w >> 6], 1);
            sh.p1.lbuf[p0] = ((unsigned)(r.x & 63) << 17) | (unsigned)cc.x;
            sh.p1.lbuf[p1] = ((unsigned)(r.y & 63) << 17) | (unsigned)cc.y;
            sh.p1.lbuf[p2] = ((unsigned)(r.z & 63) << 17) | (unsigned)cc.z;
            sh.p1.lbuf[p3] = ((unsigned)(r.w & 63) << 17) | (unsigned)cc.w;
        }
        {
            int ts = base + (nE & ~3);
            for (int e = ts + tid; e < lim; e += PT) {
                int r = rows[e];
                int p = atomicAdd(&sh.p1.lcur[r >> 6], 1);
                sh.p1.lbuf[p] = ((unsigned)(r & 63) << 17) | (unsigned)cols[e];
            }
        }
        __syncthreads();

        // pass C: copy runs to global slabs (contiguous within runs)
        const int chunk = (nE + PT - 1) / PT;
        int i0 = tid * chunk;
        int i1 = min(nE, i0 + chunk);
        if (i0 < i1) {
            int lo = 0, hi = NFX;
            while (hi - lo > 1) {
                int mid = (lo + hi) >> 1;
                if (sh.p1.loff[mid] <= i0) lo = mid; else hi = mid;
            }
            int b = lo;
            for (int i = i0; i < i1; ++i) {
                while (i >= sh.p1.loff[b + 1]) ++b;
                int pos = sh.p1.gbase[b] + (i - sh.p1.loff[b]);
                if (pos < (b + 1) * SLAB)          // slab-overflow guard
                    packed[pos] = sh.p1.lbuf[i];
            }
        }
        __syncthreads();
    }
}

// ---------------- B: per-bucket sort + gather (uint4 loads, no shfl) ----------------
__global__ __launch_bounds__(256) void sort_gather2(const unsigned* __restrict__ WTh,
                                                    const unsigned* __restrict__ packed,
                                                    const int* __restrict__ gcur,
                                                    const float* __restrict__ bias,
                                                    float* __restrict__ out, int N) {
    __shared__ unsigned scol[SLAB];           // 10 KB
    __shared__ int cw[4 * 64];                // per-wave hist, then cursors
    __shared__ int off0[64], tend[64];
    const int b    = blockIdx.x;
    const int tid  = threadIdx.x;
    const int lane = tid & 63;
    const int w    = tid >> 6;
    const int start = b * SLAB;
    int size = gcur[b];
    if (size > SLAB) size = SLAB;

    if (tid < 256) cw[tid] = 0;
    __syncthreads();
    // count: per-wave histograms (4x less contention)
    for (int e = tid; e < size; e += 256)
        atomicAdd(&cw[w * 64 + (packed[start + e] >> 17)], 1);
    __syncthreads();
    if (tid < 64) {
        int c0 = cw[tid], c1 = cw[64 + tid], c2 = cw[128 + tid], c3 = cw[192 + tid];
        int v = c0 + c1 + c2 + c3;
        int inc = v;                          // wave-0 shfl scan over 64 rows
        #pragma unroll
        for (int d = 1; d < 64; d <<= 1) {
            int t = __shfl_up(inc, d, 64);
            if (lane >= d) inc += t;
        }
        int ex = inc - v;
        off0[tid] = ex;
        tend[tid] = inc;
        cw[tid]       = ex;                   // per-wave scatter bases
        cw[64 + tid]  = ex + c0;
        cw[128 + tid] = ex + c0 + c1;
        cw[192 + tid] = ex + c0 + c1 + c2;
    }
    __syncthreads();
    for (int e = tid; e < size; e += 256) {
        unsigned u = packed[start + e];
        int p = atomicAdd(&cw[w * 64 + (u >> 17)], 1);
        scol[p] = u & 0x1FFFFu;
    }
    __syncthreads();

    // gather: 8-lane group per node; lane q loads uint4 = channels 8q..8q+7
    const int g = lane >> 3;                  // group 0..7
    const int q = lane & 7;
    const float4 b0 = *(const float4*)(bias + q * 8);
    const float4 b1 = *(const float4*)(bias + q * 8 + 4);
    #pragma unroll
    for (int rb = 0; rb < 64; rb += 32) {     // 32 nodes across 4 waves per pass
        const int r = rb + w * 8 + g;
        const int n = b * 64 + r;
        const int s = off0[r];
        const int t = tend[r];
        float a0 = 0.f, a1 = 0.f, a2 = 0.f, a3 = 0.f;
        float a4 = 0.f, a5 = 0.f, a6 = 0.f, a7 = 0.f;
        int e = s;
        while (__any(e < t)) {                // unroll 2 for load ILP
            bool p0 = (e < t), p1 = (e + 1 < t);
            unsigned c0 = p0 ? scol[e] : 0u;
            unsigned c1 = p1 ? scol[e + 1] : 0u;
            if (p0) {
                uint4 u = *(const uint4*)(WTh + (size_t)c0 * 32 + q * 4);
                a0 += bf_lo(u.x); a1 += bf_hi(u.x);
                a2 += bf_lo(u.y); a3 += bf_hi(u.y);
                a4 += bf_lo(u.z); a5 += bf_hi(u.z);
                a6 += bf_lo(u.w); a7 += bf_hi(u.w);
            }
            if (p1) {
                uint4 u = *(const uint4*)(WTh + (size_t)c1 * 32 + q * 4);
                a0 += bf_lo(u.x); a1 += bf_hi(u.x);
                a2 += bf_lo(u.y); a3 += bf_hi(u.y);
                a4 += bf_lo(u.z); a5 += bf_hi(u.z);
                a6 += bf_lo(u.w); a7 += bf_hi(u.w);
            }
            e += 2;
        }
        if (n < N) {
            float4 o1, o2;
            o1.x = a0 + b0.x; o1.y = a1 + b0.y; o1.z = a2 + b0.z; o1.w = a3 + b0.w;
            o2.x = a4 + b1.x; o2.y = a5 + b1.y; o2.z = a6 + b1.z; o2.w = a7 + b1.w;
            *(float4*)(out + (size_t)n * 64 + q * 8)     = o1;
            *(float4*)(out + (size_t)n * 64 + q * 8 + 4) = o2;
        }
    }
}

extern "C" void kernel_launch(void* const* d_in, const int* in_sizes, int n_in,
                              void* d_out, int out_size, void* d_ws, size_t ws_size,
                              hipStream_t stream) {
    const int*   edges = (const int*)d_in[0];    // [2, E]: rows then cols
    const float* W     = (const float*)d_in[1];  // [64, N]
    const float* bias  = (const float*)d_in[2];  // [64]
    float*       out   = (float*)d_out;          // [N, 64]

    const int E  = in_sizes[0] / 2;
    const int N  = in_sizes[1] / OUTC;
    const int NF = (N + 63) / 64;                // 1563 fine buckets

    // workspace layout (~29 MB)
    char* ws = (char*)d_ws;
    size_t off = 0;
    unsigned* WTh = (unsigned*)(ws + off); off += (size_t)N * 32 * sizeof(unsigned);
    off = (off + 255) & ~(size_t)255;
    int* gcur = (int*)(ws + off);          off += (size_t)NF * sizeof(int);
    off = (off + 255) & ~(size_t)255;
    unsigned* packed = (unsigned*)(ws + off); off += (size_t)NF * SLAB * sizeof(unsigned);
    (void)ws_size;

    const int* rows = edges;
    const int* cols = edges + E;

    hipMemsetAsync(gcur, 0, (size_t)NF * sizeof(int), stream);
    part_trans<<<256, PT, 0, stream>>>(rows, cols, W, WTh, gcur, packed, E, N, NF);
    sort_gather2<<<NF, 256, 0, stream>>>(WTh, packed, gcur, bias, out, N);
}